// Round 10
// baseline (76.930 us; speedup 1.0000x reference)
//
#include <hip/hip_runtime.h>

// CropperQAT: 3-level RoIAlign (8x8, sampling_ratio=1, aligned=false) with
// fake-quantized ROI coords, channel-concat output [A, 192, 8, 8] fp32.
//
// R10: two-pass (R7) structure, one (roi,lvl) per block. Compute phase
// repartitioned so each thread owns 4 consecutive positions x 4 channels ->
// output stores are 4x float4 (dwordx4 NT, 4x fewer store instrs) instead of
// 16x dword. LDS reads become 16x uint2 (exact 4ch), ~2-way conflicts.

#define NCH 64

typedef unsigned int   u32;
typedef unsigned short u16;
typedef float  vf4 __attribute__((ext_vector_type(4)));
typedef u32    vu2 __attribute__((ext_vector_type(2)));

__device__ __forceinline__ float fake_quant(float v) {
    float r = rintf(v * 4.0f);                 // round half to even, like np.round
    r = fminf(fmaxf(r, -32768.0f), 32767.0f);
    return r * 0.25f;
}

struct Prep { int lo, hi; float fr; bool valid; };
__device__ __forceinline__ Prep prep(float c, int L) {
    Prep r;
    r.valid = (c >= -1.0f) && (c <= (float)L);
    c = fmaxf(c, 0.0f);
    const int l0 = (int)floorf(c);
    const bool he = (l0 >= L - 1);
    r.lo = he ? (L - 1) : l0;
    r.hi = he ? (L - 1) : (l0 + 1);
    r.fr = (he ? (float)(L - 1) : c) - (float)r.lo;
    return r;
}

__device__ __forceinline__ u16 f2bf(float x) {          // RNE fp32 -> bf16
    u32 u = __float_as_uint(x);
    u += 0x7FFFu + ((u >> 16) & 1u);
    return (u16)(u >> 16);
}
__device__ __forceinline__ float bflo(u32 w) { return __uint_as_float(w << 16); }
__device__ __forceinline__ float bfhi(u32 w) { return __uint_as_float(w & 0xFFFF0000u); }

// ---------------- NCHW(fp32) -> NHWC(bf16) transpose, all 3 levels fused ----
__global__ __launch_bounds__(256) void nchw_to_nhwc_bf16(
    const float* __restrict__ f0, const float* __restrict__ f1,
    const float* __restrict__ f2, u16* __restrict__ n0,
    u16* __restrict__ n1, u16* __restrict__ n2)
{
    __shared__ float tile[64][65];
    const int t = threadIdx.x;
    const int b = blockIdx.y;
    const int g = blockIdx.x;
    const float* src; u16* dst; int HW; int tl;
    if (g < 1024)      { src = f0; dst = n0; HW = 65536; tl = g; }
    else if (g < 1280) { src = f1; dst = n1; HW = 16384; tl = g - 1024; }
    else               { src = f2; dst = n2; HW = 4096;  tl = g - 1280; }
    const int hw0 = tl * 64;
    const float* __restrict__ s = src + (size_t)b * 64 * HW + hw0;
    vu2* __restrict__ d = (vu2*)(dst + ((size_t)b * HW + hw0) * 64);

    const int xq = (t & 15) * 4;
    const int cb = t >> 4;                       // 0..15
    #pragma unroll
    for (int k = 0; k < 4; ++k) {
        const int c = k * 16 + cb;
        const vf4 v = __builtin_nontemporal_load(
            (const vf4*)(s + (size_t)c * HW + xq));
        tile[c][xq + 0] = v.x;
        tile[c][xq + 1] = v.y;
        tile[c][xq + 2] = v.z;
        tile[c][xq + 3] = v.w;
    }
    __syncthreads();

    #pragma unroll
    for (int k = 0; k < 4; ++k) {
        const int idx = k * 256 + t;
        const int pos = idx >> 4;
        const int c2  = idx & 15;
        vu2 w;
        w.x = (u32)f2bf(tile[4 * c2 + 0][pos])
            | ((u32)f2bf(tile[4 * c2 + 1][pos]) << 16);
        w.y = (u32)f2bf(tile[4 * c2 + 2][pos])
            | ((u32)f2bf(tile[4 * c2 + 3][pos]) << 16);
        __builtin_nontemporal_store(w, d + pos * 16 + c2);
    }
}

// ---------------- main kernel: bf16 LDS patch, float4 output stores ---------
__global__ __launch_bounds__(256) void cropper_qat_bf16(
    const u16* __restrict__ g0, const u16* __restrict__ g1,
    const u16* __restrict__ g2, const float* __restrict__ pixel,
    const int* __restrict__ bidx, float* __restrict__ out)
{
    // 81 positions x 8 chunks (uint4 = 8 bf16 channels), XOR-swizzled: 10368 B
    __shared__ uint4 tile[81 * 8];

    const int a   = blockIdx.x;
    const int lvl = blockIdx.y;

    const float inv_s = (lvl == 0) ? 0.25f : (lvl == 1) ? 0.125f : 0.0625f;
    const int   L     = (lvl == 0) ? 256   : (lvl == 1) ? 128    : 64;
    const u16* __restrict__ f = (lvl == 0) ? g0 : (lvl == 1) ? g1 : g2;

    const int   b  = bidx[a];
    const float px = pixel[2 * a];
    const float py = pixel[2 * a + 1];

    const float x1 = fake_quant(fmaxf(px * inv_s - 4.0f, 0.0f));
    const float y1 = fake_quant(fmaxf(py * inv_s - 4.0f, 0.0f));
    const float x2 = fake_quant(fmaxf(px * inv_s + 4.0f, 0.0f));
    const float y2 = fake_quant(fmaxf(py * inv_s + 4.0f, 0.0f));

    const float binw = fmaxf(x2 - x1, 1.0f) * 0.125f;   // multiples of 1/32
    const float binh = fmaxf(y2 - y1, 1.0f) * 0.125f;

    // uniform patch origin (prep is monotone in the sample coordinate)
    const int y_lo = prep(y1 + 0.5f * binh, L).lo;
    const int x_lo = prep(x1 + 0.5f * binw, L).lo;

    const int tid = threadIdx.x;

    // ---- stage fixed 9x9 patch (648 uint4 chunks); over-read stays in ws ----
    {
        const u16* __restrict__ fbase =
            f + ((size_t)b * L * L + (size_t)y_lo * L + x_lo) * NCH;
        #pragma unroll
        for (int it = 0; it < 3; ++it) {
            const int g = tid + it * 256;
            if (g < 648) {
                const int ly  = g / 72;            // 9 rows
                const int rem = g - ly * 72;       // 9 cols x 8 chunks
                const int pos = ly * 9 + (rem >> 3);
                const int c   = rem & 7;
                const uint4 v = *(const uint4*)(fbase + (size_t)ly * L * NCH + rem * 8);
                tile[pos * 8 + (c ^ (pos & 7))] = v;
            }
        }
    }
    __syncthreads();

    // ---- per-thread bilinear: 4 positions x 4 channels ----------------------
    const int s     = tid & 15;        // position segment: p = 4s..4s+3
    const int cg    = tid >> 4;        // channel quad: c = 4cg..4cg+3
    const int i     = s >> 1;          // row
    const int j0    = (s & 1) * 4;     // first col of segment
    const int chunk = cg >> 1;         // uint4 chunk (8 ch)
    const int half  = cg & 1;          // which uint2 half (4 ch)

    const vu2* __restrict__ tl2 = (const vu2*)tile;

    const Prep py_ = prep(y1 + ((float)i + 0.5f) * binh, L);
    const int r0 = (py_.lo - y_lo) * 9;
    const int r1 = (py_.hi - y_lo) * 9;
    const float wy0 = 1.0f - py_.fr, wy1 = py_.fr;

    float acc[4][4];
    #pragma unroll
    for (int q = 0; q < 4; ++q) {
        const Prep px_ = prep(x1 + ((float)(j0 + q) + 0.5f) * binw, L);
        const bool valid = py_.valid && px_.valid;
        const float wx0 = 1.0f - px_.fr, wx1 = px_.fr;
        const float w00 = wy0 * wx0, w01 = wy0 * wx1;
        const float w10 = wy1 * wx0, w11 = wy1 * wx1;
        const int cx0 = px_.lo - x_lo, cx1 = px_.hi - x_lo;
        const int p00 = r0 + cx0, p01 = r0 + cx1;
        const int p10 = r1 + cx0, p11 = r1 + cx1;

        #define LD(P) tl2[(P) * 16 + ((chunk ^ ((P) & 7)) * 2 + half)]
        const vu2 a00 = LD(p00);
        const vu2 a01 = LD(p01);
        const vu2 a10 = LD(p10);
        const vu2 a11 = LD(p11);
        #undef LD

        const float v00[4] = {bflo(a00.x), bfhi(a00.x), bflo(a00.y), bfhi(a00.y)};
        const float v01[4] = {bflo(a01.x), bfhi(a01.x), bflo(a01.y), bfhi(a01.y)};
        const float v10[4] = {bflo(a10.x), bfhi(a10.x), bflo(a10.y), bfhi(a10.y)};
        const float v11[4] = {bflo(a11.x), bfhi(a11.x), bflo(a11.y), bfhi(a11.y)};

        #pragma unroll
        for (int k = 0; k < 4; ++k) {
            const float val = v00[k] * w00 + v01[k] * w01
                            + v10[k] * w10 + v11[k] * w11;
            acc[q][k] = valid ? val : 0.0f;
        }
    }

    // ---- stores: 4x float4 (dwordx4 NT), 4 consecutive positions each -------
    float* __restrict__ outp =
        out + ((size_t)a * 192 + (size_t)lvl * NCH + (size_t)cg * 4) * 64 + s * 4;
    #pragma unroll
    for (int k = 0; k < 4; ++k) {
        vf4 f4;
        f4.x = acc[0][k]; f4.y = acc[1][k]; f4.z = acc[2][k]; f4.w = acc[3][k];
        __builtin_nontemporal_store(f4, (vf4*)(outp + (size_t)k * 64));
    }
}

// ---------------- fallback: fp32 NCHW direct gather -------------------------
__global__ __launch_bounds__(256) void cropper_qat_nchw(
    const float* __restrict__ f0, const float* __restrict__ f1,
    const float* __restrict__ f2, const float* __restrict__ pixel,
    const int* __restrict__ bidx, float* __restrict__ out)
{
    const int a   = blockIdx.x;
    const int lvl = blockIdx.y;
    const float inv_s = (lvl == 0) ? 0.25f : (lvl == 1) ? 0.125f : 0.0625f;
    const int   L     = (lvl == 0) ? 256   : (lvl == 1) ? 128    : 64;
    const float* __restrict__ f = (lvl == 0) ? f0 : (lvl == 1) ? f1 : f2;

    const int   b  = bidx[a];
    const float px = pixel[2 * a];
    const float py = pixel[2 * a + 1];
    const float x1 = fake_quant(fmaxf(px * inv_s - 4.0f, 0.0f));
    const float y1 = fake_quant(fmaxf(py * inv_s - 4.0f, 0.0f));
    const float x2 = fake_quant(fmaxf(px * inv_s + 4.0f, 0.0f));
    const float y2 = fake_quant(fmaxf(py * inv_s + 4.0f, 0.0f));
    const float binw = fmaxf(x2 - x1, 1.0f) * 0.125f;
    const float binh = fmaxf(y2 - y1, 1.0f) * 0.125f;

    const int tid = threadIdx.x;
    const int p = tid & 63, i = p >> 3, j = p & 7, c0 = tid >> 6;

    const Prep py_ = prep(y1 + ((float)i + 0.5f) * binh, L);
    const Prep px_ = prep(x1 + ((float)j + 0.5f) * binw, L);
    const bool valid = py_.valid && px_.valid;
    const float wy0 = 1.0f - py_.fr, wy1 = py_.fr;
    const float wx0 = 1.0f - px_.fr, wx1 = px_.fr;
    const float w00 = wy0 * wx0, w01 = wy0 * wx1, w10 = wy1 * wx0, w11 = wy1 * wx1;

    const size_t HW = (size_t)L * L;
    const float* __restrict__ fb = f + (size_t)b * NCH * HW;
    const int o00 = py_.lo * L + px_.lo, o01 = py_.lo * L + px_.hi;
    const int o10 = py_.hi * L + px_.lo, o11 = py_.hi * L + px_.hi;
    float* __restrict__ outp = out + ((size_t)a * 192 + (size_t)lvl * NCH) * 64 + p;

    #pragma unroll 4
    for (int c = c0; c < NCH; c += 4) {
        const float* __restrict__ fc = fb + (size_t)c * HW;
        float val = ((fc[o00] * w00 + fc[o01] * w01) + fc[o10] * w10) + fc[o11] * w11;
        outp[(size_t)c * 64] = valid ? val : 0.0f;
    }
}

extern "C" void kernel_launch(void* const* d_in, const int* in_sizes, int n_in,
                              void* d_out, int out_size, void* d_ws, size_t ws_size,
                              hipStream_t stream) {
    const float* f0    = (const float*)d_in[0];
    const float* f1    = (const float*)d_in[1];
    const float* f2    = (const float*)d_in[2];
    const float* pixel = (const float*)d_in[3];
    const int*   bidx  = (const int*)d_in[4];
    float* out = (float*)d_out;
    const int A = in_sizes[4];   // 4096 rois

    // bf16 NHWC scratch + 128KB slop for fixed-9x9 over-read past n2
    const size_t NEED = (size_t)(16777216 + 4194304 + 1048576) * 2 + 131072;
    if (ws_size >= NEED) {
        u16* n0 = (u16*)d_ws;
        u16* n1 = n0 + 16777216;
        u16* n2 = n1 + 4194304;
        nchw_to_nhwc_bf16<<<dim3(1344, 4), 256, 0, stream>>>(f0, f1, f2, n0, n1, n2);
        cropper_qat_bf16<<<dim3(A, 3), 256, 0, stream>>>(n0, n1, n2, pixel, bidx, out);
    } else {
        cropper_qat_nchw<<<dim3(A, 3), 256, 0, stream>>>(f0, f1, f2, pixel, bidx, out);
    }
}

// Round 11
// 73.201 us; speedup vs baseline: 1.0509x; 1.0509x over previous
//
#include <hip/hip_runtime.h>

// CropperQAT: 3-level RoIAlign (8x8, sampling_ratio=1, aligned=false) with
// fake-quantized ROI coords, channel-concat output [A, 192, 8, 8] fp32.
//
// R11: two-pass (R7) structure; main-kernel staging now uses
// __builtin_amdgcn_global_load_lds (16B/lane, 1KB/wave-instr, 11 instrs/block)
// with the XOR swizzle pre-applied to the per-lane GLOBAL source address and
// a linear LDS destination (m173 pattern). Removes the global->VGPR->ds_write
// round-trip. Compute/store phase identical to R4 (best measured: 75.8).

#define NCH 64

typedef unsigned int   u32;
typedef unsigned short u16;
typedef float  vf4 __attribute__((ext_vector_type(4)));
typedef u32    vu2 __attribute__((ext_vector_type(2)));

__device__ __forceinline__ float fake_quant(float v) {
    float r = rintf(v * 4.0f);                 // round half to even, like np.round
    r = fminf(fmaxf(r, -32768.0f), 32767.0f);
    return r * 0.25f;
}

struct Prep { int lo, hi; float fr; bool valid; };
__device__ __forceinline__ Prep prep(float c, int L) {
    Prep r;
    r.valid = (c >= -1.0f) && (c <= (float)L);
    c = fmaxf(c, 0.0f);
    const int l0 = (int)floorf(c);
    const bool he = (l0 >= L - 1);
    r.lo = he ? (L - 1) : l0;
    r.hi = he ? (L - 1) : (l0 + 1);
    r.fr = (he ? (float)(L - 1) : c) - (float)r.lo;
    return r;
}

__device__ __forceinline__ u16 f2bf(float x) {          // RNE fp32 -> bf16
    u32 u = __float_as_uint(x);
    u += 0x7FFFu + ((u >> 16) & 1u);
    return (u16)(u >> 16);
}
__device__ __forceinline__ float bflo(u32 w) { return __uint_as_float(w << 16); }
__device__ __forceinline__ float bfhi(u32 w) { return __uint_as_float(w & 0xFFFF0000u); }

// ---------------- NCHW(fp32) -> NHWC(bf16) transpose, all 3 levels fused ----
__global__ __launch_bounds__(256) void nchw_to_nhwc_bf16(
    const float* __restrict__ f0, const float* __restrict__ f1,
    const float* __restrict__ f2, u16* __restrict__ n0,
    u16* __restrict__ n1, u16* __restrict__ n2)
{
    __shared__ float tile[64][65];
    const int t = threadIdx.x;
    const int b = blockIdx.y;
    const int g = blockIdx.x;
    const float* src; u16* dst; int HW; int tl;
    if (g < 1024)      { src = f0; dst = n0; HW = 65536; tl = g; }
    else if (g < 1280) { src = f1; dst = n1; HW = 16384; tl = g - 1024; }
    else               { src = f2; dst = n2; HW = 4096;  tl = g - 1280; }
    const int hw0 = tl * 64;
    const float* __restrict__ s = src + (size_t)b * 64 * HW + hw0;
    vu2* __restrict__ d = (vu2*)(dst + ((size_t)b * HW + hw0) * 64);

    const int xq = (t & 15) * 4;
    const int cb = t >> 4;                       // 0..15
    #pragma unroll
    for (int k = 0; k < 4; ++k) {
        const int c = k * 16 + cb;
        const vf4 v = __builtin_nontemporal_load(
            (const vf4*)(s + (size_t)c * HW + xq));
        tile[c][xq + 0] = v.x;
        tile[c][xq + 1] = v.y;
        tile[c][xq + 2] = v.z;
        tile[c][xq + 3] = v.w;
    }
    __syncthreads();

    #pragma unroll
    for (int k = 0; k < 4; ++k) {
        const int idx = k * 256 + t;
        const int pos = idx >> 4;
        const int c2  = idx & 15;
        vu2 w;
        w.x = (u32)f2bf(tile[4 * c2 + 0][pos])
            | ((u32)f2bf(tile[4 * c2 + 1][pos]) << 16);
        w.y = (u32)f2bf(tile[4 * c2 + 2][pos])
            | ((u32)f2bf(tile[4 * c2 + 3][pos]) << 16);
        __builtin_nontemporal_store(w, d + pos * 16 + c2);
    }
}

// ---------------- main kernel: global_load_lds staging + R4 compute ---------
__global__ __launch_bounds__(256) void cropper_qat_bf16(
    const u16* __restrict__ g0, const u16* __restrict__ g1,
    const u16* __restrict__ g2, const float* __restrict__ pixel,
    const int* __restrict__ bidx, float* __restrict__ out)
{
    // 704 linear uint4 units (11 x 64); logical unit g = pos*8 + c', where the
    // SOURCE chunk is c = c' ^ (pos & 7) (swizzle pre-applied to global addr).
    __shared__ uint4 tile[704];

    const int a   = blockIdx.x;
    const int lvl = blockIdx.y;

    const float inv_s = (lvl == 0) ? 0.25f : (lvl == 1) ? 0.125f : 0.0625f;
    const int   L     = (lvl == 0) ? 256   : (lvl == 1) ? 128    : 64;
    const u16* __restrict__ f = (lvl == 0) ? g0 : (lvl == 1) ? g1 : g2;

    const int   b  = bidx[a];
    const float px = pixel[2 * a];
    const float py = pixel[2 * a + 1];

    const float x1 = fake_quant(fmaxf(px * inv_s - 4.0f, 0.0f));
    const float y1 = fake_quant(fmaxf(py * inv_s - 4.0f, 0.0f));
    const float x2 = fake_quant(fmaxf(px * inv_s + 4.0f, 0.0f));
    const float y2 = fake_quant(fmaxf(py * inv_s + 4.0f, 0.0f));

    const float binw = fmaxf(x2 - x1, 1.0f) * 0.125f;   // multiples of 1/32
    const float binh = fmaxf(y2 - y1, 1.0f) * 0.125f;

    // uniform patch origin (prep is monotone in the sample coordinate)
    const int y_lo = prep(y1 + 0.5f * binh, L).lo;
    const int x_lo = prep(x1 + 0.5f * binw, L).lo;

    const int tid  = threadIdx.x;
    const int wave = tid >> 6;
    const int lane = tid & 63;

    // ---- stage 9x9 patch: 11 wave-level global_load_lds (1KB each) ----------
    {
        const u16* __restrict__ fbase =
            f + ((size_t)b * L * L + (size_t)y_lo * L + x_lo) * NCH;
        #pragma unroll
        for (int kb = wave; kb < 11; kb += 4) {     // wave-uniform iteration
            const int g  = kb * 64 + lane;          // linear LDS unit
            const int gc = (g < 648) ? g : 647;     // tail: duplicate source
            const int pos = gc >> 3;                // 0..80
            const int c   = (gc & 7) ^ (pos & 7);   // pre-swizzled source chunk
            const int ly  = pos / 9;
            const int lx  = pos - ly * 9;
            const u16* src = fbase + ((size_t)(ly * L + lx)) * NCH + c * 8;
            __builtin_amdgcn_global_load_lds(
                (const __attribute__((address_space(1))) u32*)src,
                (__attribute__((address_space(3))) u32*)&tile[kb * 64],
                16, 0, 0);
        }
    }
    __syncthreads();   // drains vmcnt(0): all LDS-DMA complete

    // ---- per-thread bilinear from LDS (identical to R4) ---------------------
    const int p  = tid & 63;
    const int i  = p >> 3;
    const int j  = p & 7;
    const int c0 = tid >> 6;       // 16-channel group = chunks 2c0, 2c0+1

    const Prep py_ = prep(y1 + ((float)i + 0.5f) * binh, L);
    const Prep px_ = prep(x1 + ((float)j + 0.5f) * binw, L);
    const bool valid = py_.valid && px_.valid;

    const float wy0 = 1.0f - py_.fr, wy1 = py_.fr;
    const float wx0 = 1.0f - px_.fr, wx1 = px_.fr;
    const float w00 = wy0 * wx0, w01 = wy0 * wx1;
    const float w10 = wy1 * wx0, w11 = wy1 * wx1;

    const int r0 = (py_.lo - y_lo) * 9;
    const int r1 = (py_.hi - y_lo) * 9;
    const int pos00 = r0 + (px_.lo - x_lo);
    const int pos01 = r0 + (px_.hi - x_lo);
    const int pos10 = r1 + (px_.lo - x_lo);
    const int pos11 = r1 + (px_.hi - x_lo);

    float r[16];
    #pragma unroll
    for (int k = 0; k < 16; ++k) r[k] = 0.0f;

    #define CORNER(POS, W) {                                                  \
        const uint4 qa = tile[(POS) * 8 + ((2 * c0)     ^ ((POS) & 7))];      \
        const uint4 qb = tile[(POS) * 8 + ((2 * c0 + 1) ^ ((POS) & 7))];      \
        r[0]  += bflo(qa.x) * (W); r[1]  += bfhi(qa.x) * (W);                 \
        r[2]  += bflo(qa.y) * (W); r[3]  += bfhi(qa.y) * (W);                 \
        r[4]  += bflo(qa.z) * (W); r[5]  += bfhi(qa.z) * (W);                 \
        r[6]  += bflo(qa.w) * (W); r[7]  += bfhi(qa.w) * (W);                 \
        r[8]  += bflo(qb.x) * (W); r[9]  += bfhi(qb.x) * (W);                 \
        r[10] += bflo(qb.y) * (W); r[11] += bfhi(qb.y) * (W);                 \
        r[12] += bflo(qb.z) * (W); r[13] += bfhi(qb.z) * (W);                 \
        r[14] += bflo(qb.w) * (W); r[15] += bfhi(qb.w) * (W); }

    CORNER(pos00, w00)
    CORNER(pos01, w01)
    CORNER(pos10, w10)
    CORNER(pos11, w11)
    #undef CORNER

    float* __restrict__ outp =
        out + ((size_t)a * 192 + (size_t)lvl * NCH + (size_t)c0 * 16) * 64 + p;
    #pragma unroll
    for (int k = 0; k < 16; ++k)
        __builtin_nontemporal_store(valid ? r[k] : 0.0f, outp + (size_t)k * 64);
}

// ---------------- fallback: fp32 NCHW direct gather -------------------------
__global__ __launch_bounds__(256) void cropper_qat_nchw(
    const float* __restrict__ f0, const float* __restrict__ f1,
    const float* __restrict__ f2, const float* __restrict__ pixel,
    const int* __restrict__ bidx, float* __restrict__ out)
{
    const int a   = blockIdx.x;
    const int lvl = blockIdx.y;
    const float inv_s = (lvl == 0) ? 0.25f : (lvl == 1) ? 0.125f : 0.0625f;
    const int   L     = (lvl == 0) ? 256   : (lvl == 1) ? 128    : 64;
    const float* __restrict__ f = (lvl == 0) ? f0 : (lvl == 1) ? f1 : f2;

    const int   b  = bidx[a];
    const float px = pixel[2 * a];
    const float py = pixel[2 * a + 1];
    const float x1 = fake_quant(fmaxf(px * inv_s - 4.0f, 0.0f));
    const float y1 = fake_quant(fmaxf(py * inv_s - 4.0f, 0.0f));
    const float x2 = fake_quant(fmaxf(px * inv_s + 4.0f, 0.0f));
    const float y2 = fake_quant(fmaxf(py * inv_s + 4.0f, 0.0f));
    const float binw = fmaxf(x2 - x1, 1.0f) * 0.125f;
    const float binh = fmaxf(y2 - y1, 1.0f) * 0.125f;

    const int tid = threadIdx.x;
    const int p = tid & 63, i = p >> 3, j = p & 7, c0 = tid >> 6;

    const Prep py_ = prep(y1 + ((float)i + 0.5f) * binh, L);
    const Prep px_ = prep(x1 + ((float)j + 0.5f) * binw, L);
    const bool valid = py_.valid && px_.valid;
    const float wy0 = 1.0f - py_.fr, wy1 = py_.fr;
    const float wx0 = 1.0f - px_.fr, wx1 = px_.fr;
    const float w00 = wy0 * wx0, w01 = wy0 * wx1, w10 = wy1 * wx0, w11 = wy1 * wx1;

    const size_t HW = (size_t)L * L;
    const float* __restrict__ fb = f + (size_t)b * NCH * HW;
    const int o00 = py_.lo * L + px_.lo, o01 = py_.lo * L + px_.hi;
    const int o10 = py_.hi * L + px_.lo, o11 = py_.hi * L + px_.hi;
    float* __restrict__ outp = out + ((size_t)a * 192 + (size_t)lvl * NCH) * 64 + p;

    #pragma unroll 4
    for (int c = c0; c < NCH; c += 4) {
        const float* __restrict__ fc = fb + (size_t)c * HW;
        float val = ((fc[o00] * w00 + fc[o01] * w01) + fc[o10] * w10) + fc[o11] * w11;
        outp[(size_t)c * 64] = valid ? val : 0.0f;
    }
}

extern "C" void kernel_launch(void* const* d_in, const int* in_sizes, int n_in,
                              void* d_out, int out_size, void* d_ws, size_t ws_size,
                              hipStream_t stream) {
    const float* f0    = (const float*)d_in[0];
    const float* f1    = (const float*)d_in[1];
    const float* f2    = (const float*)d_in[2];
    const float* pixel = (const float*)d_in[3];
    const int*   bidx  = (const int*)d_in[4];
    float* out = (float*)d_out;
    const int A = in_sizes[4];   // 4096 rois

    // bf16 NHWC scratch + 128KB slop for fixed-9x9 over-read past n2
    const size_t NEED = (size_t)(16777216 + 4194304 + 1048576) * 2 + 131072;
    if (ws_size >= NEED) {
        u16* n0 = (u16*)d_ws;
        u16* n1 = n0 + 16777216;
        u16* n2 = n1 + 4194304;
        nchw_to_nhwc_bf16<<<dim3(1344, 4), 256, 0, stream>>>(f0, f1, f2, n0, n1, n2);
        cropper_qat_bf16<<<dim3(A, 3), 256, 0, stream>>>(n0, n1, n2, pixel, bidx, out);
    } else {
        cropper_qat_nchw<<<dim3(A, 3), 256, 0, stream>>>(f0, f1, f2, pixel, bidx, out);
    }
}

// Round 12
// 71.606 us; speedup vs baseline: 1.0744x; 1.0223x over previous
//
#include <hip/hip_runtime.h>

// CropperQAT: 3-level RoIAlign (8x8, sampling_ratio=1, aligned=false) with
// fake-quantized ROI coords, channel-concat output [A, 192, 8, 8] fp32.
//
// R12: R11 + transpose NHWC writes are now PLAIN stores (not nontemporal):
// the intermediate is producer->consumer data consumed by the very next
// kernel; NT was pushing it to HBM and defeating L3 retention. NT kept on
// read-once fp32 loads and on final output stores (never re-read).

#define NCH 64

typedef unsigned int   u32;
typedef unsigned short u16;
typedef float  vf4 __attribute__((ext_vector_type(4)));
typedef u32    vu2 __attribute__((ext_vector_type(2)));

__device__ __forceinline__ float fake_quant(float v) {
    float r = rintf(v * 4.0f);                 // round half to even, like np.round
    r = fminf(fmaxf(r, -32768.0f), 32767.0f);
    return r * 0.25f;
}

struct Prep { int lo, hi; float fr; bool valid; };
__device__ __forceinline__ Prep prep(float c, int L) {
    Prep r;
    r.valid = (c >= -1.0f) && (c <= (float)L);
    c = fmaxf(c, 0.0f);
    const int l0 = (int)floorf(c);
    const bool he = (l0 >= L - 1);
    r.lo = he ? (L - 1) : l0;
    r.hi = he ? (L - 1) : (l0 + 1);
    r.fr = (he ? (float)(L - 1) : c) - (float)r.lo;
    return r;
}

__device__ __forceinline__ u16 f2bf(float x) {          // RNE fp32 -> bf16
    u32 u = __float_as_uint(x);
    u += 0x7FFFu + ((u >> 16) & 1u);
    return (u16)(u >> 16);
}
__device__ __forceinline__ float bflo(u32 w) { return __uint_as_float(w << 16); }
__device__ __forceinline__ float bfhi(u32 w) { return __uint_as_float(w & 0xFFFF0000u); }

// ---------------- NCHW(fp32) -> NHWC(bf16) transpose, all 3 levels fused ----
__global__ __launch_bounds__(256) void nchw_to_nhwc_bf16(
    const float* __restrict__ f0, const float* __restrict__ f1,
    const float* __restrict__ f2, u16* __restrict__ n0,
    u16* __restrict__ n1, u16* __restrict__ n2)
{
    __shared__ float tile[64][65];
    const int t = threadIdx.x;
    const int b = blockIdx.y;
    const int g = blockIdx.x;
    const float* src; u16* dst; int HW; int tl;
    if (g < 1024)      { src = f0; dst = n0; HW = 65536; tl = g; }
    else if (g < 1280) { src = f1; dst = n1; HW = 16384; tl = g - 1024; }
    else               { src = f2; dst = n2; HW = 4096;  tl = g - 1280; }
    const int hw0 = tl * 64;
    const float* __restrict__ s = src + (size_t)b * 64 * HW + hw0;
    vu2* __restrict__ d = (vu2*)(dst + ((size_t)b * HW + hw0) * 64);

    const int xq = (t & 15) * 4;
    const int cb = t >> 4;                       // 0..15
    #pragma unroll
    for (int k = 0; k < 4; ++k) {
        const int c = k * 16 + cb;
        const vf4 v = __builtin_nontemporal_load(
            (const vf4*)(s + (size_t)c * HW + xq));
        tile[c][xq + 0] = v.x;
        tile[c][xq + 1] = v.y;
        tile[c][xq + 2] = v.z;
        tile[c][xq + 3] = v.w;
    }
    __syncthreads();

    // PLAIN stores: intermediate is consumed by the next kernel -> keep in L2/L3
    #pragma unroll
    for (int k = 0; k < 4; ++k) {
        const int idx = k * 256 + t;
        const int pos = idx >> 4;
        const int c2  = idx & 15;
        vu2 w;
        w.x = (u32)f2bf(tile[4 * c2 + 0][pos])
            | ((u32)f2bf(tile[4 * c2 + 1][pos]) << 16);
        w.y = (u32)f2bf(tile[4 * c2 + 2][pos])
            | ((u32)f2bf(tile[4 * c2 + 3][pos]) << 16);
        d[pos * 16 + c2] = w;
    }
}

// ---------------- main kernel: global_load_lds staging + R4 compute ---------
__global__ __launch_bounds__(256) void cropper_qat_bf16(
    const u16* __restrict__ g0, const u16* __restrict__ g1,
    const u16* __restrict__ g2, const float* __restrict__ pixel,
    const int* __restrict__ bidx, float* __restrict__ out)
{
    // 704 linear uint4 units (11 x 64); logical unit g = pos*8 + c', where the
    // SOURCE chunk is c = c' ^ (pos & 7) (swizzle pre-applied to global addr).
    __shared__ uint4 tile[704];

    const int a   = blockIdx.x;
    const int lvl = blockIdx.y;

    const float inv_s = (lvl == 0) ? 0.25f : (lvl == 1) ? 0.125f : 0.0625f;
    const int   L     = (lvl == 0) ? 256   : (lvl == 1) ? 128    : 64;
    const u16* __restrict__ f = (lvl == 0) ? g0 : (lvl == 1) ? g1 : g2;

    const int   b  = bidx[a];
    const float px = pixel[2 * a];
    const float py = pixel[2 * a + 1];

    const float x1 = fake_quant(fmaxf(px * inv_s - 4.0f, 0.0f));
    const float y1 = fake_quant(fmaxf(py * inv_s - 4.0f, 0.0f));
    const float x2 = fake_quant(fmaxf(px * inv_s + 4.0f, 0.0f));
    const float y2 = fake_quant(fmaxf(py * inv_s + 4.0f, 0.0f));

    const float binw = fmaxf(x2 - x1, 1.0f) * 0.125f;   // multiples of 1/32
    const float binh = fmaxf(y2 - y1, 1.0f) * 0.125f;

    // uniform patch origin (prep is monotone in the sample coordinate)
    const int y_lo = prep(y1 + 0.5f * binh, L).lo;
    const int x_lo = prep(x1 + 0.5f * binw, L).lo;

    const int tid  = threadIdx.x;
    const int wave = tid >> 6;
    const int lane = tid & 63;

    // ---- stage 9x9 patch: 11 wave-level global_load_lds (1KB each) ----------
    {
        const u16* __restrict__ fbase =
            f + ((size_t)b * L * L + (size_t)y_lo * L + x_lo) * NCH;
        #pragma unroll
        for (int kb = wave; kb < 11; kb += 4) {     // wave-uniform iteration
            const int g  = kb * 64 + lane;          // linear LDS unit
            const int gc = (g < 648) ? g : 647;     // tail: duplicate source
            const int pos = gc >> 3;                // 0..80
            const int c   = (gc & 7) ^ (pos & 7);   // pre-swizzled source chunk
            const int ly  = pos / 9;
            const int lx  = pos - ly * 9;
            const u16* src = fbase + ((size_t)(ly * L + lx)) * NCH + c * 8;
            __builtin_amdgcn_global_load_lds(
                (const __attribute__((address_space(1))) u32*)src,
                (__attribute__((address_space(3))) u32*)&tile[kb * 64],
                16, 0, 0);
        }
    }
    __syncthreads();   // drains vmcnt(0): all LDS-DMA complete

    // ---- per-thread bilinear from LDS (identical to R4) ---------------------
    const int p  = tid & 63;
    const int i  = p >> 3;
    const int j  = p & 7;
    const int c0 = tid >> 6;       // 16-channel group = chunks 2c0, 2c0+1

    const Prep py_ = prep(y1 + ((float)i + 0.5f) * binh, L);
    const Prep px_ = prep(x1 + ((float)j + 0.5f) * binw, L);
    const bool valid = py_.valid && px_.valid;

    const float wy0 = 1.0f - py_.fr, wy1 = py_.fr;
    const float wx0 = 1.0f - px_.fr, wx1 = px_.fr;
    const float w00 = wy0 * wx0, w01 = wy0 * wx1;
    const float w10 = wy1 * wx0, w11 = wy1 * wx1;

    const int r0 = (py_.lo - y_lo) * 9;
    const int r1 = (py_.hi - y_lo) * 9;
    const int pos00 = r0 + (px_.lo - x_lo);
    const int pos01 = r0 + (px_.hi - x_lo);
    const int pos10 = r1 + (px_.lo - x_lo);
    const int pos11 = r1 + (px_.hi - x_lo);

    float r[16];
    #pragma unroll
    for (int k = 0; k < 16; ++k) r[k] = 0.0f;

    #define CORNER(POS, W) {                                                  \
        const uint4 qa = tile[(POS) * 8 + ((2 * c0)     ^ ((POS) & 7))];      \
        const uint4 qb = tile[(POS) * 8 + ((2 * c0 + 1) ^ ((POS) & 7))];      \
        r[0]  += bflo(qa.x) * (W); r[1]  += bfhi(qa.x) * (W);                 \
        r[2]  += bflo(qa.y) * (W); r[3]  += bfhi(qa.y) * (W);                 \
        r[4]  += bflo(qa.z) * (W); r[5]  += bfhi(qa.z) * (W);                 \
        r[6]  += bflo(qa.w) * (W); r[7]  += bfhi(qa.w) * (W);                 \
        r[8]  += bflo(qb.x) * (W); r[9]  += bfhi(qb.x) * (W);                 \
        r[10] += bflo(qb.y) * (W); r[11] += bfhi(qb.y) * (W);                 \
        r[12] += bflo(qb.z) * (W); r[13] += bfhi(qb.z) * (W);                 \
        r[14] += bflo(qb.w) * (W); r[15] += bfhi(qb.w) * (W); }

    CORNER(pos00, w00)
    CORNER(pos01, w01)
    CORNER(pos10, w10)
    CORNER(pos11, w11)
    #undef CORNER

    float* __restrict__ outp =
        out + ((size_t)a * 192 + (size_t)lvl * NCH + (size_t)c0 * 16) * 64 + p;
    #pragma unroll
    for (int k = 0; k < 16; ++k)
        __builtin_nontemporal_store(valid ? r[k] : 0.0f, outp + (size_t)k * 64);
}

// ---------------- fallback: fp32 NCHW direct gather -------------------------
__global__ __launch_bounds__(256) void cropper_qat_nchw(
    const float* __restrict__ f0, const float* __restrict__ f1,
    const float* __restrict__ f2, const float* __restrict__ pixel,
    const int* __restrict__ bidx, float* __restrict__ out)
{
    const int a   = blockIdx.x;
    const int lvl = blockIdx.y;
    const float inv_s = (lvl == 0) ? 0.25f : (lvl == 1) ? 0.125f : 0.0625f;
    const int   L     = (lvl == 0) ? 256   : (lvl == 1) ? 128    : 64;
    const float* __restrict__ f = (lvl == 0) ? f0 : (lvl == 1) ? f1 : f2;

    const int   b  = bidx[a];
    const float px = pixel[2 * a];
    const float py = pixel[2 * a + 1];
    const float x1 = fake_quant(fmaxf(px * inv_s - 4.0f, 0.0f));
    const float y1 = fake_quant(fmaxf(py * inv_s - 4.0f, 0.0f));
    const float x2 = fake_quant(fmaxf(px * inv_s + 4.0f, 0.0f));
    const float y2 = fake_quant(fmaxf(py * inv_s + 4.0f, 0.0f));
    const float binw = fmaxf(x2 - x1, 1.0f) * 0.125f;
    const float binh = fmaxf(y2 - y1, 1.0f) * 0.125f;

    const int tid = threadIdx.x;
    const int p = tid & 63, i = p >> 3, j = p & 7, c0 = tid >> 6;

    const Prep py_ = prep(y1 + ((float)i + 0.5f) * binh, L);
    const Prep px_ = prep(x1 + ((float)j + 0.5f) * binw, L);
    const bool valid = py_.valid && px_.valid;
    const float wy0 = 1.0f - py_.fr, wy1 = py_.fr;
    const float wx0 = 1.0f - px_.fr, wx1 = px_.fr;
    const float w00 = wy0 * wx0, w01 = wy0 * wx1, w10 = wy1 * wx0, w11 = wy1 * wx1;

    const size_t HW = (size_t)L * L;
    const float* __restrict__ fb = f + (size_t)b * NCH * HW;
    const int o00 = py_.lo * L + px_.lo, o01 = py_.lo * L + px_.hi;
    const int o10 = py_.hi * L + px_.lo, o11 = py_.hi * L + px_.hi;
    float* __restrict__ outp = out + ((size_t)a * 192 + (size_t)lvl * NCH) * 64 + p;

    #pragma unroll 4
    for (int c = c0; c < NCH; c += 4) {
        const float* __restrict__ fc = fb + (size_t)c * HW;
        float val = ((fc[o00] * w00 + fc[o01] * w01) + fc[o10] * w10) + fc[o11] * w11;
        outp[(size_t)c * 64] = valid ? val : 0.0f;
    }
}

extern "C" void kernel_launch(void* const* d_in, const int* in_sizes, int n_in,
                              void* d_out, int out_size, void* d_ws, size_t ws_size,
                              hipStream_t stream) {
    const float* f0    = (const float*)d_in[0];
    const float* f1    = (const float*)d_in[1];
    const float* f2    = (const float*)d_in[2];
    const float* pixel = (const float*)d_in[3];
    const int*   bidx  = (const int*)d_in[4];
    float* out = (float*)d_out;
    const int A = in_sizes[4];   // 4096 rois

    // bf16 NHWC scratch + 128KB slop for fixed-9x9 over-read past n2
    const size_t NEED = (size_t)(16777216 + 4194304 + 1048576) * 2 + 131072;
    if (ws_size >= NEED) {
        u16* n0 = (u16*)d_ws;
        u16* n1 = n0 + 16777216;
        u16* n2 = n1 + 4194304;
        nchw_to_nhwc_bf16<<<dim3(1344, 4), 256, 0, stream>>>(f0, f1, f2, n0, n1, n2);
        cropper_qat_bf16<<<dim3(A, 3), 256, 0, stream>>>(n0, n1, n2, pixel, bidx, out);
    } else {
        cropper_qat_nchw<<<dim3(A, 3), 256, 0, stream>>>(f0, f1, f2, pixel, bidx, out);
    }
}